// Round 1
// baseline (297.813 us; speedup 1.0000x reference)
//
#include <hip/hip_runtime.h>
#include <hip/hip_bf16.h>

// attention_11269994185437: B=4, C=256, CQK=32, H=W=64 -> N=4096
// out = gamma * (V @ P) + x,  P[n,m] = softmax_m-row-n of (QtK), rows normalized over m.
// Phase 1: proj -> Qt[b][n][32], Kt[b][n][32] (transposed, bf16), Vb[b][c][n] (bf16)
// Phase 2: rowstats: rowmax[b][n], rowinv[b][n] over S = Q^T K
// Phase 3: fused out[c,m] = sum_n Vb[c,n] * exp2((S[n,m]-max[n])*L2E)*inv[n]; y = g*out + x

#define NB 4
#define CC 256
#define NN 4096
#define L2E 1.44269504088896340f

typedef short  short4v  __attribute__((ext_vector_type(4)));
typedef short  short8v  __attribute__((ext_vector_type(8)));
typedef __bf16 bf16x8   __attribute__((ext_vector_type(8)));
typedef float  f32x4    __attribute__((ext_vector_type(4)));
typedef float  f32x16   __attribute__((ext_vector_type(16)));

static __device__ __forceinline__ unsigned short f2bf(float f) {
  union { float f; unsigned u; } v; v.f = f;
  unsigned r = v.u + 0x7FFFu + ((v.u >> 16) & 1u);   // RNE
  return (unsigned short)(r >> 16);
}

union FragU { short8v s; bf16x8 b; };

static __device__ __forceinline__ bf16x8 ld_frag(const unsigned short* p) {
  FragU u; u.s = *(const short8v*)p; return u.b;
}

static __device__ __forceinline__ f32x16 zero16() {
  f32x16 v;
#pragma unroll
  for (int i = 0; i < 16; ++i) v[i] = 0.0f;
  return v;
}

static __device__ __forceinline__ f32x16 mfma32(bf16x8 a, bf16x8 b, f32x16 c) {
  return __builtin_amdgcn_mfma_f32_32x32x16_bf16(a, b, c, 0, 0, 0);
}

// ---------------- Kernel 1: QKV projection --------------------------------
// grid (N/64, B), block 256 (4 waves). Out tile: all 320 d-rows x 64 n.
// M-frags f: 0 -> Q (rows 0..31), 1 -> K, 2..9 -> V rows (f-2)*32..
__global__ __launch_bounds__(256) void k_proj(
    const float* __restrict__ x,
    const float* __restrict__ Wq, const float* __restrict__ bq,
    const float* __restrict__ Wk, const float* __restrict__ bk,
    const float* __restrict__ Wv, const float* __restrict__ bv,
    unsigned short* __restrict__ Qt, unsigned short* __restrict__ Kt,
    unsigned short* __restrict__ Vb)
{
  __shared__ unsigned short xs[64][268];   // xs[n_local][c], pad 268: b64 reads ~conflict-free
  const int t = threadIdx.x;
  const int b = blockIdx.y;
  const int n0 = blockIdx.x * 64;
  const int w = t >> 6, l = t & 63, h = l >> 5, col = l & 31;

  const float* xb = x + (size_t)b * CC * NN;
  // stage x[c][n0..n0+63] transposed into LDS as bf16
  for (int c = w; c < CC; c += 4)
    xs[l][c] = f2bf(xb[(size_t)c * NN + n0 + l]);
  __syncthreads();

  for (int f = w; f < 10; f += 4) {
    const float* Wsrc; const float* bsrc; int rowbase; int mode;
    if (f == 0)      { Wsrc = Wq; bsrc = bq; rowbase = 0;            mode = 0; }
    else if (f == 1) { Wsrc = Wk; bsrc = bk; rowbase = 0;            mode = 1; }
    else             { Wsrc = Wv; bsrc = bv; rowbase = (f - 2) * 32; mode = 2; }

    f32x16 acc0 = zero16(), acc1 = zero16();
    const float* wr = Wsrc + (size_t)(rowbase + col) * CC + 8 * h;   // A row = col

#pragma unroll
    for (int k0 = 0; k0 < CC; k0 += 16) {
      // A frag: W[row=col][k0 + 8h + j], f32 -> bf16
      f32x4 w0 = *(const f32x4*)(wr + k0);
      f32x4 w1 = *(const f32x4*)(wr + k0 + 4);
      FragU a;
#pragma unroll
      for (int j = 0; j < 4; ++j) { a.s[j] = (short)f2bf(w0[j]); a.s[4 + j] = (short)f2bf(w1[j]); }
      // B frags: xs[n_local][k0 + 8h + j], n_local = 32*nf + col
      const unsigned short* p0 = &xs[col][k0 + 8 * h];
      const unsigned short* p1 = &xs[32 + col][k0 + 8 * h];
      FragU b0, b1;
      short4v t0a = *(const short4v*)p0, t0b = *(const short4v*)(p0 + 4);
      short4v t1a = *(const short4v*)p1, t1b = *(const short4v*)(p1 + 4);
#pragma unroll
      for (int j = 0; j < 4; ++j) {
        b0.s[j] = t0a[j]; b0.s[4 + j] = t0b[j];
        b1.s[j] = t1a[j]; b1.s[4 + j] = t1b[j];
      }
      acc0 = mfma32(a.b, b0.b, acc0);
      acc1 = mfma32(a.b, b1.b, acc1);
    }

    // epilogue: D row (out d_local) = (r&3) + 8*(r>>2) + 4h, col (n_local) = l&31
#pragma unroll
    for (int nf = 0; nf < 2; ++nf) {
      f32x16 A = nf ? acc1 : acc0;
      const int n = n0 + 32 * nf + col;
#pragma unroll
      for (int q = 0; q < 4; ++q) {
        f32x4 bias4 = *(const f32x4*)(bsrc + rowbase + 8 * q + 4 * h);
        float vals[4];
#pragma unroll
        for (int i = 0; i < 4; ++i) vals[i] = A[4 * q + i] + bias4[i];
        if (mode == 2) {
#pragma unroll
          for (int i = 0; i < 4; ++i) {
            int c = rowbase + 8 * q + 4 * h + i;
            Vb[((size_t)b * CC + c) * NN + n] = f2bf(vals[i]);
          }
        } else {
          unsigned short* dst = (mode == 0) ? Qt : Kt;
          short4v s4;
#pragma unroll
          for (int i = 0; i < 4; ++i) s4[i] = (short)f2bf(vals[i]);
          *(short4v*)(dst + ((size_t)b * NN + n) * 32 + 8 * q + 4 * h) = s4;
        }
      }
    }
  }
}

// ---------------- Kernel 2: row stats (max, 1/sum) ------------------------
// grid (N/32, B), block 64 (1 wave). Wave owns 32 n-rows, sweeps all m.
// Two sweeps: max, then sum of exp2((S-max)*L2E). Row n lives in 32 lanes of
// half h=((n-n0)>>2)&1 at reg r; butterfly-reduce within the half.
__global__ __launch_bounds__(64) void k_rowstats(
    const unsigned short* __restrict__ Qt, const unsigned short* __restrict__ Kt,
    float* __restrict__ rowmax, float* __restrict__ rowinv)
{
  const int l = threadIdx.x, h = l >> 5, col = l & 31;
  const int b = blockIdx.y;
  const int n0 = blockIdx.x * 32;
  const unsigned short* Qb = Qt + (size_t)b * NN * 32;
  const unsigned short* Kb = Kt + (size_t)b * NN * 32;

  bf16x8 aq0 = ld_frag(Qb + (size_t)(n0 + col) * 32 + 8 * h);
  bf16x8 aq1 = ld_frag(Qb + (size_t)(n0 + col) * 32 + 16 + 8 * h);

  float mx[16];
#pragma unroll
  for (int r = 0; r < 16; ++r) mx[r] = -3.4e38f;

  for (int m0 = 0; m0 < NN; m0 += 32) {
    bf16x8 bk0 = ld_frag(Kb + (size_t)(m0 + col) * 32 + 8 * h);
    bf16x8 bk1 = ld_frag(Kb + (size_t)(m0 + col) * 32 + 16 + 8 * h);
    f32x16 S = zero16();
    S = mfma32(aq0, bk0, S);
    S = mfma32(aq1, bk1, S);
#pragma unroll
    for (int r = 0; r < 16; ++r) mx[r] = fmaxf(mx[r], S[r]);
  }
#pragma unroll
  for (int off = 1; off < 32; off <<= 1)
#pragma unroll
    for (int r = 0; r < 16; ++r) mx[r] = fmaxf(mx[r], __shfl_xor(mx[r], off));

  float sm[16];
#pragma unroll
  for (int r = 0; r < 16; ++r) sm[r] = 0.0f;

  for (int m0 = 0; m0 < NN; m0 += 32) {
    bf16x8 bk0 = ld_frag(Kb + (size_t)(m0 + col) * 32 + 8 * h);
    bf16x8 bk1 = ld_frag(Kb + (size_t)(m0 + col) * 32 + 16 + 8 * h);
    f32x16 S = zero16();
    S = mfma32(aq0, bk0, S);
    S = mfma32(aq1, bk1, S);
#pragma unroll
    for (int r = 0; r < 16; ++r) sm[r] += exp2f((S[r] - mx[r]) * L2E);
  }
#pragma unroll
  for (int off = 1; off < 32; off <<= 1)
#pragma unroll
    for (int r = 0; r < 16; ++r) sm[r] += __shfl_xor(sm[r], off);

  if (col == 0) {
#pragma unroll
    for (int r = 0; r < 16; ++r) {
      int n = n0 + (r & 3) + 8 * (r >> 2) + 4 * h;
      rowmax[(size_t)b * NN + n] = mx[r];
      rowinv[(size_t)b * NN + n] = 1.0f / sm[r];
    }
  }
}

// ---------------- Kernel 3: fused out = g * (V @ P) + x -------------------
// grid (N/64, B), block 256 (4 waves). Wave w: c-half ch=w&1 (128 c = 4 frags),
// m-frag mf=w>>1 (32 m). Loop n in 32-steps: S via MFMA, E = exp*inv through
// per-wave LDS scratch, then 8 MFMAs accumulate V@E.
__global__ __launch_bounds__(256) void k_attn_out(
    const unsigned short* __restrict__ Qt, const unsigned short* __restrict__ Kt,
    const unsigned short* __restrict__ Vb,
    const float* __restrict__ rowmax, const float* __restrict__ rowinv,
    const float* __restrict__ x, const float* __restrict__ gamma,
    float* __restrict__ out)
{
  __shared__ float El[4][32][33];   // per-wave E scratch [n_local][m_local], pad 33
  const int t = threadIdx.x;
  const int w = t >> 6, l = t & 63, h = l >> 5, col = l & 31;
  const int b = blockIdx.y;
  const int m0 = blockIdx.x * 64;
  const int ch = w & 1, mf = w >> 1;
  const int cbase = 128 * ch;
  const int m = m0 + 32 * mf + col;

  const unsigned short* Qb  = Qt + (size_t)b * NN * 32;
  const unsigned short* Kb  = Kt + (size_t)b * NN * 32;
  const unsigned short* Vbb = Vb + (size_t)b * CC * NN;
  const float* rm = rowmax + (size_t)b * NN;
  const float* ri = rowinv + (size_t)b * NN;

  // K fragments for this wave's m-columns are loop-invariant
  bf16x8 bk0 = ld_frag(Kb + (size_t)m * 32 + 8 * h);
  bf16x8 bk1 = ld_frag(Kb + (size_t)m * 32 + 16 + 8 * h);

  f32x16 acc[4];
#pragma unroll
  for (int cf = 0; cf < 4; ++cf) acc[cf] = zero16();

  for (int nn = 0; nn < NN; nn += 32) {
    bf16x8 aq0 = ld_frag(Qb + (size_t)(nn + col) * 32 + 8 * h);
    bf16x8 aq1 = ld_frag(Qb + (size_t)(nn + col) * 32 + 16 + 8 * h);
    f32x16 S = zero16();
    S = mfma32(aq0, bk0, S);
    S = mfma32(aq1, bk1, S);

    // E = exp2((S - rowmax)*L2E) * rowinv, staged to LDS
#pragma unroll
    for (int q = 0; q < 4; ++q) {
      f32x4 rm4 = *(const f32x4*)(rm + nn + 8 * q + 4 * h);
      f32x4 ri4 = *(const f32x4*)(ri + nn + 8 * q + 4 * h);
#pragma unroll
      for (int i = 0; i < 4; ++i)
        El[w][8 * q + 4 * h + i][col] = exp2f((S[4 * q + i] - rm4[i]) * L2E) * ri4[i];
    }

    // consume E as B-fragments; A = V rows (contiguous along n)
#pragma unroll
    for (int kh = 0; kh < 2; ++kh) {
      FragU be;
#pragma unroll
      for (int j = 0; j < 8; ++j)
        be.s[j] = (short)f2bf(El[w][16 * kh + 8 * h + j][col]);
#pragma unroll
      for (int cf = 0; cf < 4; ++cf) {
        bf16x8 av = ld_frag(Vbb + (size_t)(cbase + 32 * cf + col) * NN + nn + 16 * kh + 8 * h);
        acc[cf] = mfma32(av, be.b, acc[cf]);
      }
    }
  }

  const float g = gamma[0];
#pragma unroll
  for (int cf = 0; cf < 4; ++cf) {
#pragma unroll
    for (int r = 0; r < 16; ++r) {
      int c = cbase + 32 * cf + (r & 3) + 8 * (r >> 2) + 4 * h;
      size_t idx = ((size_t)b * CC + c) * NN + m;
      out[idx] = g * acc[cf][r] + x[idx];
    }
  }
}

// ---------------- launch ---------------------------------------------------
extern "C" void kernel_launch(void* const* d_in, const int* in_sizes, int n_in,
                              void* d_out, int out_size, void* d_ws, size_t ws_size,
                              hipStream_t stream) {
  const float* x     = (const float*)d_in[0];
  const float* Wq    = (const float*)d_in[1];
  const float* bq    = (const float*)d_in[2];
  const float* Wk    = (const float*)d_in[3];
  const float* bk    = (const float*)d_in[4];
  const float* Wv    = (const float*)d_in[5];
  const float* bv    = (const float*)d_in[6];
  const float* gamma = (const float*)d_in[7];
  float* out = (float*)d_out;

  char* ws = (char*)d_ws;
  unsigned short* Qt = (unsigned short*)(ws);                     // 1 MB
  unsigned short* Kt = (unsigned short*)(ws + (1u << 20));        // 1 MB
  unsigned short* Vb = (unsigned short*)(ws + (2u << 20));        // 8 MB
  float* rowmax = (float*)(ws + (10u << 20));                     // 64 KB
  float* rowinv = (float*)(ws + (10u << 20) + (1u << 16));        // 64 KB

  k_proj<<<dim3(NN / 64, NB), 256, 0, stream>>>(x, Wq, bq, Wk, bk, Wv, bv, Qt, Kt, Vb);
  k_rowstats<<<dim3(NN / 32, NB), 64, 0, stream>>>(Qt, Kt, rowmax, rowinv);
  k_attn_out<<<dim3(NN / 64, NB), 256, 0, stream>>>(Qt, Kt, Vb, rowmax, rowinv, x, gamma, out);
}

// Round 2
// 210.205 us; speedup vs baseline: 1.4168x; 1.4168x over previous
//
#include <hip/hip_runtime.h>
#include <hip/hip_bf16.h>

// attention_11269994185437: B=4, C=256, CQK=32, H=W=64 -> N=4096
// out = gamma * (V @ P) + x,  P[n,m] = softmax over m of S[n,m], S = Q^T K.
// k_proj      : x -> Qt[b][n][32], Kt[b][n][32] (bf16, transposed), Vb[b][c][n] (bf16)
// k_rowstats_part (4-way m-split) + k_statfin -> cbias[b][n] = -max*L2E - log2(sum)
// k_attn_out  : out[c,m] = g * sum_n V[c,n]*exp2(S[n,m]*L2E + cbias[n]) + x[c,m]
//               E relayout done in-register via v_permlane32_swap_b32 (T12), no LDS.

#define NB 4
#define CC 256
#define NN 4096
#define MSPLIT 4
#define L2E 1.44269504088896340f

typedef short  short4v  __attribute__((ext_vector_type(4)));
typedef short  short8v  __attribute__((ext_vector_type(8)));
typedef __bf16 bf16x8   __attribute__((ext_vector_type(8)));
typedef float  f32x4    __attribute__((ext_vector_type(4)));
typedef float  f32x16   __attribute__((ext_vector_type(16)));

static __device__ __forceinline__ unsigned short f2bf(float f) {
  union { __bf16 h; unsigned short u; } v; v.h = (__bf16)f; return v.u;
}

union FragU { short8v s; bf16x8 b; unsigned u[4]; };
union PackU { __bf16 h[8]; unsigned u[4]; };

static __device__ __forceinline__ bf16x8 ld_frag(const unsigned short* p) {
  FragU u; u.s = *(const short8v*)p; return u.b;
}

static __device__ __forceinline__ f32x16 zero16() {
  f32x16 v;
#pragma unroll
  for (int i = 0; i < 16; ++i) v[i] = 0.0f;
  return v;
}

static __device__ __forceinline__ f32x16 mfma32(bf16x8 a, bf16x8 b, f32x16 c) {
  return __builtin_amdgcn_mfma_f32_32x32x16_bf16(a, b, c, 0, 0, 0);
}

// ---------------- Kernel 1: QKV projection --------------------------------
// grid (N/64, B), block 256 (4 waves). M-frags f: 0->Q, 1->K, 2..9->V rows.
__global__ __launch_bounds__(256) void k_proj(
    const float* __restrict__ x,
    const float* __restrict__ Wq, const float* __restrict__ bq,
    const float* __restrict__ Wk, const float* __restrict__ bk,
    const float* __restrict__ Wv, const float* __restrict__ bv,
    unsigned short* __restrict__ Qt, unsigned short* __restrict__ Kt,
    unsigned short* __restrict__ Vb)
{
  __shared__ unsigned short xs[64][268];   // xs[n_local][c]
  const int t = threadIdx.x;
  const int b = blockIdx.y;
  const int n0 = blockIdx.x * 64;
  const int w = t >> 6, l = t & 63, h = l >> 5, col = l & 31;

  const float* xb = x + (size_t)b * CC * NN;
  // stage x[c][n0..n0+63] transposed into LDS as bf16; f32x4 loads along n
  {
    const int c_off = t >> 4, nl = 4 * (t & 15);
#pragma unroll
    for (int c0 = 0; c0 < CC; c0 += 16) {
      int c = c0 + c_off;
      f32x4 v4 = *(const f32x4*)(xb + (size_t)c * NN + n0 + nl);
#pragma unroll
      for (int j = 0; j < 4; ++j) xs[nl + j][c] = f2bf(v4[j]);
    }
  }
  __syncthreads();

  for (int f = w; f < 10; f += 4) {
    const float* Wsrc; const float* bsrc; int rowbase; int mode;
    if (f == 0)      { Wsrc = Wq; bsrc = bq; rowbase = 0;            mode = 0; }
    else if (f == 1) { Wsrc = Wk; bsrc = bk; rowbase = 0;            mode = 1; }
    else             { Wsrc = Wv; bsrc = bv; rowbase = (f - 2) * 32; mode = 2; }

    f32x16 acc0 = zero16(), acc1 = zero16();
    const float* wr = Wsrc + (size_t)(rowbase + col) * CC + 8 * h;   // A row = col

#pragma unroll
    for (int k0 = 0; k0 < CC; k0 += 16) {
      f32x4 w0 = *(const f32x4*)(wr + k0);
      f32x4 w1 = *(const f32x4*)(wr + k0 + 4);
      FragU a;
#pragma unroll
      for (int j = 0; j < 4; ++j) { a.s[j] = (short)f2bf(w0[j]); a.s[4 + j] = (short)f2bf(w1[j]); }
      const unsigned short* p0 = &xs[col][k0 + 8 * h];
      const unsigned short* p1 = &xs[32 + col][k0 + 8 * h];
      FragU b0, b1;
      short4v t0a = *(const short4v*)p0, t0b = *(const short4v*)(p0 + 4);
      short4v t1a = *(const short4v*)p1, t1b = *(const short4v*)(p1 + 4);
#pragma unroll
      for (int j = 0; j < 4; ++j) {
        b0.s[j] = t0a[j]; b0.s[4 + j] = t0b[j];
        b1.s[j] = t1a[j]; b1.s[4 + j] = t1b[j];
      }
      acc0 = mfma32(a.b, b0.b, acc0);
      acc1 = mfma32(a.b, b1.b, acc1);
    }

#pragma unroll
    for (int nf = 0; nf < 2; ++nf) {
      f32x16 A = nf ? acc1 : acc0;
      const int n = n0 + 32 * nf + col;
#pragma unroll
      for (int q = 0; q < 4; ++q) {
        f32x4 bias4 = *(const f32x4*)(bsrc + rowbase + 8 * q + 4 * h);
        float vals[4];
#pragma unroll
        for (int i = 0; i < 4; ++i) vals[i] = A[4 * q + i] + bias4[i];
        if (mode == 2) {
#pragma unroll
          for (int i = 0; i < 4; ++i) {
            int c = rowbase + 8 * q + 4 * h + i;
            Vb[((size_t)b * CC + c) * NN + n] = f2bf(vals[i]);
          }
        } else {
          unsigned short* dst = (mode == 0) ? Qt : Kt;
          short4v s4;
#pragma unroll
          for (int i = 0; i < 4; ++i) s4[i] = (short)f2bf(vals[i]);
          *(short4v*)(dst + ((size_t)b * NN + n) * 32 + 8 * q + 4 * h) = s4;
        }
      }
    }
  }
}

// ---------------- Kernel 2a: partial row stats ----------------------------
// grid (N/32, B, MSPLIT), block 64. Each block: 32 n-rows, m-range 1024.
__global__ __launch_bounds__(64) void k_rowstats_part(
    const unsigned short* __restrict__ Qt, const unsigned short* __restrict__ Kt,
    float* __restrict__ pmax, float* __restrict__ psum)
{
  const int l = threadIdx.x, h = l >> 5, col = l & 31;
  const int b = blockIdx.y;
  const int n0 = blockIdx.x * 32;
  const int mbase = blockIdx.z * (NN / MSPLIT);
  const unsigned short* Qb = Qt + (size_t)b * NN * 32;
  const unsigned short* Kb = Kt + (size_t)b * NN * 32;

  bf16x8 aq0 = ld_frag(Qb + (size_t)(n0 + col) * 32 + 8 * h);
  bf16x8 aq1 = ld_frag(Qb + (size_t)(n0 + col) * 32 + 16 + 8 * h);

  float mx[16];
#pragma unroll
  for (int r = 0; r < 16; ++r) mx[r] = -3.4e38f;

  for (int m0 = mbase; m0 < mbase + NN / MSPLIT; m0 += 32) {
    bf16x8 bk0 = ld_frag(Kb + (size_t)(m0 + col) * 32 + 8 * h);
    bf16x8 bk1 = ld_frag(Kb + (size_t)(m0 + col) * 32 + 16 + 8 * h);
    f32x16 S = zero16();
    S = mfma32(aq0, bk0, S);
    S = mfma32(aq1, bk1, S);
#pragma unroll
    for (int r = 0; r < 16; ++r) mx[r] = fmaxf(mx[r], S[r]);
  }
#pragma unroll
  for (int off = 1; off < 32; off <<= 1)
#pragma unroll
    for (int r = 0; r < 16; ++r) mx[r] = fmaxf(mx[r], __shfl_xor(mx[r], off));

  float sm[16];
#pragma unroll
  for (int r = 0; r < 16; ++r) sm[r] = 0.0f;

  for (int m0 = mbase; m0 < mbase + NN / MSPLIT; m0 += 32) {
    bf16x8 bk0 = ld_frag(Kb + (size_t)(m0 + col) * 32 + 8 * h);
    bf16x8 bk1 = ld_frag(Kb + (size_t)(m0 + col) * 32 + 16 + 8 * h);
    f32x16 S = zero16();
    S = mfma32(aq0, bk0, S);
    S = mfma32(aq1, bk1, S);
#pragma unroll
    for (int r = 0; r < 16; ++r) sm[r] += exp2f((S[r] - mx[r]) * L2E);
  }
#pragma unroll
  for (int off = 1; off < 32; off <<= 1)
#pragma unroll
    for (int r = 0; r < 16; ++r) sm[r] += __shfl_xor(sm[r], off);

  if (col == 0) {
    const size_t base = ((size_t)b * MSPLIT + blockIdx.z) * NN;
#pragma unroll
    for (int r = 0; r < 16; ++r) {
      int n = n0 + (r & 3) + 8 * (r >> 2) + 4 * h;
      pmax[base + n] = mx[r];
      psum[base + n] = sm[r];
    }
  }
}

// ---------------- Kernel 2b: combine -> cbias -----------------------------
__global__ __launch_bounds__(256) void k_statfin(
    const float* __restrict__ pmax, const float* __restrict__ psum,
    float* __restrict__ cbias)
{
  const int i = blockIdx.x * 256 + threadIdx.x;     // i = b*NN + n
  const int b = i >> 12, n = i & (NN - 1);
  float pm[MSPLIT], ps[MSPLIT];
#pragma unroll
  for (int s = 0; s < MSPLIT; ++s) {
    pm[s] = pmax[((size_t)b * MSPLIT + s) * NN + n];
    ps[s] = psum[((size_t)b * MSPLIT + s) * NN + n];
  }
  float gmax = pm[0];
#pragma unroll
  for (int s = 1; s < MSPLIT; ++s) gmax = fmaxf(gmax, pm[s]);
  float gsum = 0.0f;
#pragma unroll
  for (int s = 0; s < MSPLIT; ++s) gsum += ps[s] * exp2f((pm[s] - gmax) * L2E);
  cbias[i] = -gmax * L2E - log2f(gsum);
}

// ---------------- Kernel 3: fused out = g * (V @ E) + x -------------------
// 1-D grid 256 blocks (XCD-swizzled), block 256 (4 waves).
// Wave w: ch=w&1 (128 c), mf=w>>1 (32 m). E relayout via permlane32_swap.
__global__ __launch_bounds__(256) void k_attn_out(
    const unsigned short* __restrict__ Qt, const unsigned short* __restrict__ Kt,
    const unsigned short* __restrict__ Vb,
    const float* __restrict__ cbias,
    const float* __restrict__ x, const float* __restrict__ gamma,
    float* __restrict__ out)
{
  // bijective XCD swizzle: 256 blocks, 8 XCDs, 32 contiguous blocks per XCD
  const int wg = (int)blockIdx.x;
  const int id2 = (wg & 7) * 32 + (wg >> 3);
  const int b = id2 >> 6;               // 64 m-blocks per batch
  const int m0 = (id2 & 63) * 64;

  const int t = threadIdx.x;
  const int w = t >> 6, l = t & 63, h = l >> 5, col = l & 31;
  const int ch = w & 1, mf = w >> 1;
  const int cbase = 128 * ch;
  const int m = m0 + 32 * mf + col;

  const unsigned short* Qb  = Qt + (size_t)b * NN * 32;
  const unsigned short* Kb  = Kt + (size_t)b * NN * 32;
  const unsigned short* Vbb = Vb + (size_t)b * CC * NN;
  const float* cb = cbias + (size_t)b * NN;

  // loop-invariant K fragments (B operand of S)
  bf16x8 bk0 = ld_frag(Kb + (size_t)m * 32 + 8 * h);
  bf16x8 bk1 = ld_frag(Kb + (size_t)m * 32 + 16 + 8 * h);

  // loop-invariant V row pointers
  const unsigned short* vr0 = Vbb + (size_t)(cbase + col) * NN;
  const unsigned short* vr1 = vr0 + (size_t)32 * NN;
  const unsigned short* vr2 = vr1 + (size_t)32 * NN;
  const unsigned short* vr3 = vr2 + (size_t)32 * NN;

  f32x16 acc[4];
#pragma unroll
  for (int cf = 0; cf < 4; ++cf) acc[cf] = zero16();

  for (int nn = 0; nn < NN; nn += 32) {
    bf16x8 aq0 = ld_frag(Qb + (size_t)(nn + col) * 32 + 8 * h);
    bf16x8 aq1 = ld_frag(Qb + (size_t)(nn + col) * 32 + 16 + 8 * h);
    f32x16 S = zero16();
    S = mfma32(aq0, bk0, S);
    S = mfma32(aq1, bk1, S);

    // E = exp2(S*L2E + cbias[n]); pack to bf16 pairs (cvt_pk via native casts)
    PackU p0, p1;
#pragma unroll
    for (int q = 0; q < 4; ++q) {
      f32x4 cb4 = *(const f32x4*)(cb + nn + 8 * q + 4 * h);
#pragma unroll
      for (int i = 0; i < 4; ++i) {
        float e = exp2f(fmaf(S[4 * q + i], L2E, cb4[i]));
        if (q < 2) p0.h[4 * q + i] = (__bf16)e;
        else       p1.h[4 * (q - 2) + i] = (__bf16)e;
      }
    }
    // half-wave relayout: rows {0..7|8..15} and {16..23|24..31} per lane half
    unsigned a0 = p0.u[2], c0 = p0.u[0];
    unsigned a1 = p0.u[3], c1 = p0.u[1];
    unsigned a2 = p1.u[2], c2 = p1.u[0];
    unsigned a3 = p1.u[3], c3 = p1.u[1];
    asm("v_permlane32_swap_b32 %0, %1" : "+v"(a0), "+v"(c0));
    asm("v_permlane32_swap_b32 %0, %1" : "+v"(a1), "+v"(c1));
    asm("v_permlane32_swap_b32 %0, %1" : "+v"(a2), "+v"(c2));
    asm("v_permlane32_swap_b32 %0, %1" : "+v"(a3), "+v"(c3));
    FragU be0, be1;
    be0.u[0] = c0; be0.u[1] = c1; be0.u[2] = a0; be0.u[3] = a1;
    be1.u[0] = c2; be1.u[1] = c3; be1.u[2] = a2; be1.u[3] = a3;

    bf16x8 av;
    av = ld_frag(vr0 + nn + 8 * h);      acc[0] = mfma32(av, be0.b, acc[0]);
    av = ld_frag(vr0 + nn + 16 + 8 * h); acc[0] = mfma32(av, be1.b, acc[0]);
    av = ld_frag(vr1 + nn + 8 * h);      acc[1] = mfma32(av, be0.b, acc[1]);
    av = ld_frag(vr1 + nn + 16 + 8 * h); acc[1] = mfma32(av, be1.b, acc[1]);
    av = ld_frag(vr2 + nn + 8 * h);      acc[2] = mfma32(av, be0.b, acc[2]);
    av = ld_frag(vr2 + nn + 16 + 8 * h); acc[2] = mfma32(av, be1.b, acc[2]);
    av = ld_frag(vr3 + nn + 8 * h);      acc[3] = mfma32(av, be0.b, acc[3]);
    av = ld_frag(vr3 + nn + 16 + 8 * h); acc[3] = mfma32(av, be1.b, acc[3]);
  }

  const float g = gamma[0];
#pragma unroll
  for (int cf = 0; cf < 4; ++cf) {
#pragma unroll
    for (int r = 0; r < 16; ++r) {
      int c = cbase + 32 * cf + (r & 3) + 8 * (r >> 2) + 4 * h;
      size_t idx = ((size_t)b * CC + c) * NN + m;
      out[idx] = g * acc[cf][r] + x[idx];
    }
  }
}

// ---------------- launch ---------------------------------------------------
extern "C" void kernel_launch(void* const* d_in, const int* in_sizes, int n_in,
                              void* d_out, int out_size, void* d_ws, size_t ws_size,
                              hipStream_t stream) {
  const float* x     = (const float*)d_in[0];
  const float* Wq    = (const float*)d_in[1];
  const float* bq    = (const float*)d_in[2];
  const float* Wk    = (const float*)d_in[3];
  const float* bk    = (const float*)d_in[4];
  const float* Wv    = (const float*)d_in[5];
  const float* bv    = (const float*)d_in[6];
  const float* gamma = (const float*)d_in[7];
  float* out = (float*)d_out;

  char* ws = (char*)d_ws;
  unsigned short* Qt = (unsigned short*)(ws);                      // 1 MB
  unsigned short* Kt = (unsigned short*)(ws + (1u << 20));         // 1 MB
  unsigned short* Vb = (unsigned short*)(ws + (2u << 20));         // 8 MB
  float* pmax  = (float*)(ws + (10u << 20));                       // 256 KB
  float* psum  = (float*)(ws + (10u << 20) + (1u << 18));          // 256 KB
  float* cbias = (float*)(ws + (10u << 20) + (2u << 18));          // 64 KB

  k_proj<<<dim3(NN / 64, NB), 256, 0, stream>>>(x, Wq, bq, Wk, bk, Wv, bv, Qt, Kt, Vb);
  k_rowstats_part<<<dim3(NN / 32, NB, MSPLIT), 64, 0, stream>>>(Qt, Kt, pmax, psum);
  k_statfin<<<dim3(NB * NN / 256), 256, 0, stream>>>(pmax, psum, cbias);
  k_attn_out<<<dim3(NN / 64 * NB), 256, 0, stream>>>(Qt, Kt, Vb, cbias, x, gamma, out);
}